// Round 11
// baseline (333.972 us; speedup 1.0000x reference)
//
#include <hip/hip_runtime.h>
#include <hip/hip_bf16.h>

#define Bsz 4
#define Lseq 2048
#define Dm 512
#define Hh 8
#define HD 64
#define QBLK 128
#define KT 32
#define KSPLIT 4
#define KHALF (Lseq / KSPLIT)
#define NTT (KHALF / KT)
#define PNT (Dm / 32)

typedef __attribute__((ext_vector_type(8))) _Float16 f16x8;
typedef __attribute__((ext_vector_type(4))) float f32x4;

// ---------------- Wvo fold: Wvo[h][c] = sum_d Wv[(h*64+d)*512 + c] * Wo[h*64+d]
__global__ void wvo_kernel(const float* __restrict__ Wv, const float* __restrict__ Wo,
                           float* __restrict__ Wvo) {
    int h = blockIdx.x >> 1;
    int c = (blockIdx.x & 1) * 256 + threadIdx.x;
    float acc = 0.f;
    #pragma unroll 8
    for (int d = 0; d < HD; ++d)
        acc += Wv[(size_t)(h * HD + d) * Dm + c] * Wo[h * HD + d];
    Wvo[h * Dm + c] = acc;
}

__device__ __forceinline__ void split8f(float4 x, float4 y, f16x8& h, f16x8& l) {
    float v[8] = {x.x, x.y, x.z, x.w, y.x, y.y, y.z, y.w};
    #pragma unroll
    for (int j = 0; j < 8; ++j) {
        _Float16 hh = (_Float16)v[j];
        h[j] = hh;
        l[j] = (_Float16)((v[j] - (float)hh) * 2048.0f);
    }
}

// ---------------- MFMA projection: C = hidden @ Wqk^T via f16x3 emulation.
// K output scaled by 0.125 (exact pow2 -> bit-exact score scaling folded in).
__global__ void __launch_bounds__(256, 2) proj_mfma_kernel(
    const float* __restrict__ A,
    const float* __restrict__ Wq, const float* __restrict__ Wk,
    _Float16* __restrict__ Qhp, _Float16* __restrict__ Qlp,
    _Float16* __restrict__ Khp, _Float16* __restrict__ Klp) {
    __shared__ _Float16 AhS[2][128][32];
    __shared__ _Float16 AlS[2][128][32];
    __shared__ _Float16 BhS[2][128][32];
    __shared__ _Float16 BlS[2][128][32];

    int tid = threadIdx.x;
    int lane = tid & 63, wid = tid >> 6;
    int wm = wid >> 1, wn = wid & 1;
    int r = lane & 15, g = lane >> 4;
    int m0 = blockIdx.x * 128;
    int nblk = blockIdx.y;
    bool isQ = nblk < 4;
    const float* Wsrc = isQ ? (Wq + (size_t)nblk * 128 * Dm)
                            : (Wk + (size_t)(nblk - 4) * 128 * Dm);
    _Float16* Hout = isQ ? Qhp : Khp;
    _Float16* Lout = isQ ? Qlp : Klp;
    int ncol0 = (nblk & 3) * 128;
    float oscale = isQ ? 1.0f : 0.125f;   // SCALE folded into K (pow2: bit-exact)

    int c0 = tid * 2, c1 = tid * 2 + 1;
    int ar0 = c0 >> 2, akc0 = c0 & 3;
    int ar1 = c1 >> 2, akc1 = c1 & 3;
    int asw0 = (akc0 ^ ((ar0 >> 1) & 3)) * 8;
    int asw1 = (akc1 ^ ((ar1 >> 1) & 3)) * 8;

    const float* Abase = A + (size_t)m0 * Dm;

    float4 La0, La1, La2, La3, Lb0, Lb1, Lb2, Lb3;

#define PLOAD(T) do { \
    const float* ap0 = Abase + (size_t)ar0 * Dm + (T) * 32 + akc0 * 8; \
    const float* ap1 = Abase + (size_t)ar1 * Dm + (T) * 32 + akc1 * 8; \
    const float* bp0 = Wsrc + (size_t)ar0 * Dm + (T) * 32 + akc0 * 8; \
    const float* bp1 = Wsrc + (size_t)ar1 * Dm + (T) * 32 + akc1 * 8; \
    La0 = *(const float4*)ap0; La1 = *(const float4*)(ap0 + 4); \
    La2 = *(const float4*)ap1; La3 = *(const float4*)(ap1 + 4); \
    Lb0 = *(const float4*)bp0; Lb1 = *(const float4*)(bp0 + 4); \
    Lb2 = *(const float4*)bp1; Lb3 = *(const float4*)(bp1 + 4); \
} while (0)

#define PWRITE(BUF) do { \
    f16x8 hv, lv; \
    split8f(La0, La1, hv, lv); \
    *(f16x8*)&AhS[BUF][ar0][asw0] = hv; *(f16x8*)&AlS[BUF][ar0][asw0] = lv; \
    split8f(La2, La3, hv, lv); \
    *(f16x8*)&AhS[BUF][ar1][asw1] = hv; *(f16x8*)&AlS[BUF][ar1][asw1] = lv; \
    split8f(Lb0, Lb1, hv, lv); \
    *(f16x8*)&BhS[BUF][ar0][asw0] = hv; *(f16x8*)&BlS[BUF][ar0][asw0] = lv; \
    split8f(Lb2, Lb3, hv, lv); \
    *(f16x8*)&BhS[BUF][ar1][asw1] = hv; *(f16x8*)&BlS[BUF][ar1][asw1] = lv; \
} while (0)

    f32x4 acc1[4][4], acc2[4][4];
    #pragma unroll
    for (int mr = 0; mr < 4; ++mr)
        #pragma unroll
        for (int nr = 0; nr < 4; ++nr) {
            acc1[mr][nr] = (f32x4){0.f, 0.f, 0.f, 0.f};
            acc2[mr][nr] = (f32x4){0.f, 0.f, 0.f, 0.f};
        }

    PLOAD(0);
    PWRITE(0);
    __syncthreads();

    int sw8 = (g ^ ((r >> 1) & 3)) * 8;
    for (int t = 0; t < PNT; ++t) {
        int cur = t & 1;
        if (t + 1 < PNT) PLOAD(t + 1);
        f16x8 bhf[4], blf[4];
        #pragma unroll
        for (int nr = 0; nr < 4; ++nr) {
            int row = wn * 64 + nr * 16 + r;
            bhf[nr] = *(const f16x8*)&BhS[cur][row][sw8];
            blf[nr] = *(const f16x8*)&BlS[cur][row][sw8];
        }
        #pragma unroll
        for (int mr = 0; mr < 4; ++mr) {
            int row = wm * 64 + mr * 16 + r;
            f16x8 ah = *(const f16x8*)&AhS[cur][row][sw8];
            f16x8 al = *(const f16x8*)&AlS[cur][row][sw8];
            #pragma unroll
            for (int nr = 0; nr < 4; ++nr) {
                acc1[mr][nr] = __builtin_amdgcn_mfma_f32_16x16x32_f16(ah, bhf[nr], acc1[mr][nr], 0, 0, 0);
                acc2[mr][nr] = __builtin_amdgcn_mfma_f32_16x16x32_f16(ah, blf[nr], acc2[mr][nr], 0, 0, 0);
                acc2[mr][nr] = __builtin_amdgcn_mfma_f32_16x16x32_f16(al, bhf[nr], acc2[mr][nr], 0, 0, 0);
            }
        }
        if (t + 1 < PNT) PWRITE(cur ^ 1);
        __syncthreads();
    }

    #pragma unroll
    for (int mr = 0; mr < 4; ++mr)
        #pragma unroll
        for (int nr = 0; nr < 4; ++nr)
            #pragma unroll
            for (int j = 0; j < 4; ++j) {
                float C = (acc1[mr][nr][j] + acc2[mr][nr][j] * (1.0f / 2048.0f)) * oscale;
                size_t m = (size_t)(m0 + wm * 64 + mr * 16 + g * 4 + j);
                size_t n = (size_t)(ncol0 + wn * 64 + nr * 16 + r);
                _Float16 hh = (_Float16)C;
                Hout[m * Dm + n] = hh;
                Lout[m * Dm + n] = (_Float16)((C - (float)hh) * 2048.0f);
            }
#undef PLOAD
#undef PWRITE
}

// ---------------- vo[b][h][l] = hidden[b,l,:] . Wvo[h,:]
__global__ void vo_kernel(const float* __restrict__ hidden, const float* __restrict__ Wvo,
                          float* __restrict__ vo) {
    int bh = blockIdx.x;           // 0..31
    int b = bh >> 3, h = bh & 7;
    int l = blockIdx.y * 256 + threadIdx.x;
    __shared__ float w[Dm];
    for (int i = threadIdx.x; i < Dm; i += 256) w[i] = Wvo[h * Dm + i];
    __syncthreads();
    const float* hr = hidden + ((size_t)b * Lseq + l) * Dm;
    float a0 = 0.f, a1 = 0.f, a2 = 0.f, a3 = 0.f;
    #pragma unroll 8
    for (int c = 0; c < Dm; c += 4) {
        float4 v = *(const float4*)(hr + c);
        a0 += v.x * w[c]; a1 += v.y * w[c + 1]; a2 += v.z * w[c + 2]; a3 += v.w * w[c + 3];
    }
    vo[(size_t)bh * Lseq + l] = (a0 + a1) + (a2 + a3);
}

// ---------------- MFMA attention v9: KT=32 + KSPLIT=4 -> 18 KB LDS, 8 blocks/CU
// (100% wave occupancy), double-buffered staging, R10-trimmed epilogue.
__global__ void __launch_bounds__(256, 8) attn_mfma_kernel(
    const _Float16* __restrict__ Qhp, const _Float16* __restrict__ Qlp,
    const _Float16* __restrict__ Khp, const _Float16* __restrict__ Klp,
    const float* __restrict__ vo, double* __restrict__ Yp, double* __restrict__ Zp) {
    int tid = threadIdx.x;
    int wid = tid >> 6, lane = tid & 63;
    int blk = blockIdx.x;
    int bh = blk & 31;             // same-bh blocks -> same XCD
    int rest = blk >> 5;
    int qblk = rest & 15;          // 0..15
    int ks = rest >> 4;            // 0..3
    int b = bh >> 3, h = bh & 7;
    int q0 = qblk * QBLK + wid * 32;
    int k0 = ks * KHALF;
    int r = lane & 15, g = lane >> 4;

    __shared__ _Float16 KhS[2][KT][64];
    __shared__ _Float16 KlS[2][KT][64];
    __shared__ float vos[KHALF];

    const _Float16* Kh_g = Khp + ((size_t)(b * Lseq + k0)) * Dm + h * HD;
    const _Float16* Kl_g = Klp + ((size_t)(b * Lseq + k0)) * Dm + h * HD;

    // staging: 256 chunks/plane (row 0..31, col8 0..7), 1 chunk per thread per plane
    int srow = tid >> 3;           // 0..31
    int scol8 = tid & 7;           // 0..7
    int sgo = srow * Dm + scol8 * 8;
    int dw = (scol8 * 8) ^ ((srow & 7) << 3);

    // prologue: issue tile-0 loads
    f16x8 nh = *(const f16x8*)(Kh_g + sgo);
    f16x8 nl = *(const f16x8*)(Kl_g + sgo);

    // Q fragments (2 per wave)
    f16x8 Qh[2][2], Ql[2][2];
    #pragma unroll
    for (int f = 0; f < 2; ++f) {
        size_t qbase = ((size_t)(b * Lseq + q0 + f * 16 + r)) * Dm + h * HD + g * 8;
        Qh[f][0] = *(const f16x8*)(Qhp + qbase);
        Qh[f][1] = *(const f16x8*)(Qhp + qbase + 32);
        Ql[f][0] = *(const f16x8*)(Qlp + qbase);
        Ql[f][1] = *(const f16x8*)(Qlp + qbase + 32);
    }

    // vo slice for this k-quarter into LDS
    for (int i = tid; i < KHALF; i += 256) vos[i] = vo[(size_t)bh * Lseq + k0 + i];

    // write tile 0
    *(f16x8*)&KhS[0][srow][dw] = nh;
    *(f16x8*)&KlS[0][srow][dw] = nl;
    __syncthreads();

    double Yd[2] = {0.0, 0.0}, Zd[2] = {0.0, 0.0};
    int i0 = (g * 8) ^ ((r & 7) << 3);

    for (int t = 0; t < NTT; ++t) {
        int cur = t & 1;
        if (t + 1 < NTT) {
            size_t kn = (size_t)(t + 1) * KT * Dm;
            nh = *(const f16x8*)(Kh_g + kn + sgo);
            nl = *(const f16x8*)(Kl_g + kn + sgo);
        }
        float Yt[2] = {0.f, 0.f}, Zt[2] = {0.f, 0.f};
        #pragma unroll
        for (int s = 0; s < 2; ++s) {
            int row = s * 16 + r;
            f16x8 ah0 = *(const f16x8*)&KhS[cur][row][i0];
            f16x8 ah1 = *(const f16x8*)&KhS[cur][row][i0 ^ 32];
            f16x8 al0 = *(const f16x8*)&KlS[cur][row][i0];
            f16x8 al1 = *(const f16x8*)&KlS[cur][row][i0 ^ 32];
            float4 vkv = *(const float4*)&vos[t * KT + s * 16 + g * 4];
            float vk[4] = {vkv.x, vkv.y, vkv.z, vkv.w};
            #pragma unroll
            for (int f = 0; f < 2; ++f) {
                f32x4 acc1 = {0.f, 0.f, 0.f, 0.f};
                f32x4 acc2 = {0.f, 0.f, 0.f, 0.f};
                acc1 = __builtin_amdgcn_mfma_f32_16x16x32_f16(ah0, Qh[f][0], acc1, 0, 0, 0);
                acc1 = __builtin_amdgcn_mfma_f32_16x16x32_f16(ah1, Qh[f][1], acc1, 0, 0, 0);
                acc2 = __builtin_amdgcn_mfma_f32_16x16x32_f16(ah0, Ql[f][0], acc2, 0, 0, 0);
                acc2 = __builtin_amdgcn_mfma_f32_16x16x32_f16(ah1, Ql[f][1], acc2, 0, 0, 0);
                acc2 = __builtin_amdgcn_mfma_f32_16x16x32_f16(al0, Qh[f][0], acc2, 0, 0, 0);
                acc2 = __builtin_amdgcn_mfma_f32_16x16x32_f16(al1, Qh[f][1], acc2, 0, 0, 0);
                float Ych = 0.f, Zch = 0.f;
                #pragma unroll
                for (int j = 0; j < 4; ++j) {
                    float e = __expf(fmaf(acc2[j], 1.0f / 2048.0f, acc1[j]));
                    Ych += e * vk[j];
                    Zch += e;
                }
                Yt[f] += Ych;
                Zt[f] += Zch;
            }
        }
        Yd[0] += (double)Yt[0]; Zd[0] += (double)Zt[0];
        Yd[1] += (double)Yt[1]; Zd[1] += (double)Zt[1];
        __syncthreads();
        if (t + 1 < NTT) {
            int nxt = cur ^ 1;
            *(f16x8*)&KhS[nxt][srow][dw] = nh;
            *(f16x8*)&KlS[nxt][srow][dw] = nl;
        }
        __syncthreads();
    }

    #pragma unroll
    for (int f = 0; f < 2; ++f) {
        double Y = Yd[f], Z = Zd[f];
        Y += __shfl_xor(Y, 16, 64);
        Y += __shfl_xor(Y, 32, 64);
        Z += __shfl_xor(Z, 16, 64);
        Z += __shfl_xor(Z, 32, 64);
        if (lane < 16) {
            size_t idx = ((size_t)bh * Lseq + q0 + f * 16 + lane) * KSPLIT + ks;
            Yp[idx] = Y;
            Zp[idx] = Z;
        }
    }
}

// ---------------- boundary logits -> hard bits
__global__ void blhard_kernel(const double* __restrict__ Yp, const double* __restrict__ Zp,
                              const float* __restrict__ u, int* __restrict__ hard) {
    int i = blockIdx.x * 256 + threadIdx.x;   // b*L + l
    int b = i >> 11, l = i & (Lseq - 1);
    float bl = 0.f;
    #pragma unroll
    for (int h = 0; h < Hh; ++h) {
        size_t base = ((size_t)(b * Hh + h) * Lseq + l) * KSPLIT;
        double Y = (Yp[base] + Yp[base + 1]) + (Yp[base + 2] + Yp[base + 3]);
        double Z = (Zp[base] + Zp[base + 1]) + (Zp[base + 2] + Zp[base + 3]);
        bl += (float)(Y / Z);
    }
    float x = bl + 1.0f;                       // + boundary_scores (== 1 exactly)
    float probs = 1.0f / (1.0f + expf(-x));
    probs = fminf(fmaxf(probs, 0.0f), 1.0f);
    float pl = logf(probs) - log1pf(-probs);
    float un = u[i];
    float noise = logf(un) - log1pf(-un);
    float t = pl + noise;
    float soft = 1.0f / (1.0f + expf(-t));
    hard[i] = (soft > 0.5f) ? 1 : 0;
}

// ---------------- per-batch scan: segment starts/ends + boundary count
__global__ void scan_kernel(const int* __restrict__ hard, int* __restrict__ segstart,
                            int* __restrict__ segend, int* __restrict__ kcount) {
    int b = blockIdx.x;
    int tid = threadIdx.x;
    __shared__ int hs[Lseq];
    __shared__ int chunk[256];
    for (int i = tid; i < Lseq; i += 256) {
        segstart[b * Lseq + i] = 0;
        segend[b * Lseq + i] = 0;
    }
    int base = b * Lseq;
    int sum = 0;
    int loc[8];
    #pragma unroll
    for (int j = 0; j < 8; ++j) {
        int v = hard[base + tid * 8 + j];
        hs[tid * 8 + j] = v;
        loc[j] = sum;
        sum += v;
    }
    chunk[tid] = sum;
    __syncthreads();
    for (int off = 1; off < 256; off <<= 1) {
        int v = (tid >= off) ? chunk[tid - off] : 0;
        __syncthreads();
        chunk[tid] += v;
        __syncthreads();
    }
    int ebase = chunk[tid] - sum;  // exclusive prefix of chunks
    #pragma unroll
    for (int j = 0; j < 8; ++j) {
        int ll = tid * 8 + j;
        int id = ebase + loc[j];
        if (ll == 0 || hs[ll - 1] == 1) segstart[b * Lseq + id] = ll;
        if (ll == Lseq - 1 || hs[ll] == 1) segend[b * Lseq + id] = ll + 1;
    }
    if (tid == 255) kcount[b] = chunk[255];
}

// ---------------- pooled[b,s,d] = mean of hidden over segment range (0 if empty)
__global__ void pool_kernel(const float* __restrict__ hidden, const int* __restrict__ segstart,
                            const int* __restrict__ segend, float* __restrict__ out) {
    int i = blockIdx.x * 256 + threadIdx.x;     // < B*L*D = 2^22
    int d = i & (Dm - 1);
    int s = (i >> 9) & (Lseq - 1);
    int b = i >> 20;
    int st = segstart[b * Lseq + s];
    int en = segend[b * Lseq + s];
    int n = en - st;
    float acc = 0.f;
    for (int l = st; l < en; ++l)
        acc += hidden[((size_t)b * Lseq + l) * Dm + d];
    out[i] = (n > 0) ? acc / (float)n : 0.0f;
}

// ---------------- binomial log-prob loss
__global__ void loss_kernel(const int* __restrict__ kcount, float* __restrict__ out) {
    if (threadIdx.x == 0 && blockIdx.x == 0) {
        float n = (float)Lseq;
        float acc = 0.f;
        for (int b = 0; b < Bsz; ++b) {
            float k = (float)kcount[b];
            float lp = lgammaf(n + 1.0f) - lgammaf(k + 1.0f) - lgammaf(n - k + 1.0f)
                     + k * logf(0.2f) + (n - k) * log1pf(-0.2f);
            acc += lp;
        }
        out[(size_t)Bsz * Lseq * Dm] = -(acc / (float)Bsz) / n;
    }
}

extern "C" void kernel_launch(void* const* d_in, const int* in_sizes, int n_in,
                              void* d_out, int out_size, void* d_ws, size_t ws_size,
                              hipStream_t stream) {
    const float* hidden = (const float*)d_in[0];
    const float* Wq = (const float*)d_in[1];
    const float* Wk = (const float*)d_in[2];
    const float* Wv = (const float*)d_in[3];
    const float* Wo = (const float*)d_in[4];
    const float* u  = (const float*)d_in[5];
    float* out = (float*)d_out;

    char* ws = (char*)d_ws;
    size_t off = 0;
    const size_t plane = (size_t)Bsz * Lseq * Dm * sizeof(_Float16);   // 8 MB
    _Float16* Qhp = (_Float16*)(ws + off); off += plane;
    _Float16* Qlp = (_Float16*)(ws + off); off += plane;
    _Float16* Khp = (_Float16*)(ws + off); off += plane;
    _Float16* Klp = (_Float16*)(ws + off); off += plane;
    float* Wvo = (float*)(ws + off); off += (size_t)Hh * Dm * 4;
    float* vo = (float*)(ws + off);  off += (size_t)Bsz * Hh * Lseq * 4;
    double* Yp = (double*)(ws + off); off += (size_t)Bsz * Hh * Lseq * KSPLIT * 8;
    double* Zp = (double*)(ws + off); off += (size_t)Bsz * Hh * Lseq * KSPLIT * 8;
    int* hard = (int*)(ws + off);    off += (size_t)Bsz * Lseq * 4;
    int* segstart = (int*)(ws + off); off += (size_t)Bsz * Lseq * 4;
    int* segend = (int*)(ws + off);  off += (size_t)Bsz * Lseq * 4;
    int* kcount = (int*)(ws + off);  off += 64;

    wvo_kernel<<<dim3(16), dim3(256), 0, stream>>>(Wv, Wo, Wvo);
    proj_mfma_kernel<<<dim3((Bsz * Lseq) / 128, 8), dim3(256), 0, stream>>>(
        hidden, Wq, Wk, Qhp, Qlp, Khp, Klp);
    vo_kernel<<<dim3(Bsz * Hh, Lseq / 256), dim3(256), 0, stream>>>(hidden, Wvo, vo);
    attn_mfma_kernel<<<dim3(32 * (Lseq / QBLK) * KSPLIT), dim3(256), 0, stream>>>(
        Qhp, Qlp, Khp, Klp, vo, Yp, Zp);
    blhard_kernel<<<dim3((Bsz * Lseq) / 256), dim3(256), 0, stream>>>(Yp, Zp, u, hard);
    scan_kernel<<<dim3(Bsz), dim3(256), 0, stream>>>(hard, segstart, segend, kcount);
    pool_kernel<<<dim3((Bsz * Lseq * Dm) / 256), dim3(256), 0, stream>>>(hidden, segstart, segend, out);
    loss_kernel<<<dim3(1), dim3(64), 0, stream>>>(kcount, out);
}

// Round 12
// 141.999 us; speedup vs baseline: 2.3519x; 2.3519x over previous
//
#include <hip/hip_runtime.h>
#include <hip/hip_bf16.h>

#define Bsz 4
#define Lseq 2048
#define Dm 512
#define Hh 8
#define HD 64
#define QBLK 128
#define KT 64
#define NT (Lseq / KT)
#define PNT (Dm / 32)

typedef __attribute__((ext_vector_type(8))) _Float16 f16x8;
typedef __attribute__((ext_vector_type(4))) float f32x4;

// ---------------- Wvo fold: Wvo[h][c] = sum_d Wv[(h*64+d)*512 + c] * Wo[h*64+d]
__global__ void wvo_kernel(const float* __restrict__ Wv, const float* __restrict__ Wo,
                           float* __restrict__ Wvo) {
    int h = blockIdx.x >> 1;
    int c = (blockIdx.x & 1) * 256 + threadIdx.x;
    float acc = 0.f;
    #pragma unroll 8
    for (int d = 0; d < HD; ++d)
        acc += Wv[(size_t)(h * HD + d) * Dm + c] * Wo[h * HD + d];
    Wvo[h * Dm + c] = acc;
}

__device__ __forceinline__ void split8f(float4 x, float4 y, f16x8& h, f16x8& l) {
    float v[8] = {x.x, x.y, x.z, x.w, y.x, y.y, y.z, y.w};
    #pragma unroll
    for (int j = 0; j < 8; ++j) {
        _Float16 hh = (_Float16)v[j];
        h[j] = hh;
        l[j] = (_Float16)((v[j] - (float)hh) * 2048.0f);
    }
}

// ---------------- MFMA projection: C = hidden @ Wqk^T via f16x3 emulation.
// K output scaled by 0.125 (exact pow2 -> bit-exact score scaling folded in).
__global__ void __launch_bounds__(256, 2) proj_mfma_kernel(
    const float* __restrict__ A,
    const float* __restrict__ Wq, const float* __restrict__ Wk,
    _Float16* __restrict__ Qhp, _Float16* __restrict__ Qlp,
    _Float16* __restrict__ Khp, _Float16* __restrict__ Klp) {
    __shared__ _Float16 AhS[2][128][32];
    __shared__ _Float16 AlS[2][128][32];
    __shared__ _Float16 BhS[2][128][32];
    __shared__ _Float16 BlS[2][128][32];

    int tid = threadIdx.x;
    int lane = tid & 63, wid = tid >> 6;
    int wm = wid >> 1, wn = wid & 1;
    int r = lane & 15, g = lane >> 4;
    int m0 = blockIdx.x * 128;
    int nblk = blockIdx.y;
    bool isQ = nblk < 4;
    const float* Wsrc = isQ ? (Wq + (size_t)nblk * 128 * Dm)
                            : (Wk + (size_t)(nblk - 4) * 128 * Dm);
    _Float16* Hout = isQ ? Qhp : Khp;
    _Float16* Lout = isQ ? Qlp : Klp;
    int ncol0 = (nblk & 3) * 128;
    float oscale = isQ ? 1.0f : 0.125f;   // SCALE folded into K (pow2: bit-exact)

    int c0 = tid * 2, c1 = tid * 2 + 1;
    int ar0 = c0 >> 2, akc0 = c0 & 3;
    int ar1 = c1 >> 2, akc1 = c1 & 3;
    int asw0 = (akc0 ^ ((ar0 >> 1) & 3)) * 8;
    int asw1 = (akc1 ^ ((ar1 >> 1) & 3)) * 8;

    const float* Abase = A + (size_t)m0 * Dm;

    float4 La0, La1, La2, La3, Lb0, Lb1, Lb2, Lb3;

#define PLOAD(T) do { \
    const float* ap0 = Abase + (size_t)ar0 * Dm + (T) * 32 + akc0 * 8; \
    const float* ap1 = Abase + (size_t)ar1 * Dm + (T) * 32 + akc1 * 8; \
    const float* bp0 = Wsrc + (size_t)ar0 * Dm + (T) * 32 + akc0 * 8; \
    const float* bp1 = Wsrc + (size_t)ar1 * Dm + (T) * 32 + akc1 * 8; \
    La0 = *(const float4*)ap0; La1 = *(const float4*)(ap0 + 4); \
    La2 = *(const float4*)ap1; La3 = *(const float4*)(ap1 + 4); \
    Lb0 = *(const float4*)bp0; Lb1 = *(const float4*)(bp0 + 4); \
    Lb2 = *(const float4*)bp1; Lb3 = *(const float4*)(bp1 + 4); \
} while (0)

#define PWRITE(BUF) do { \
    f16x8 hv, lv; \
    split8f(La0, La1, hv, lv); \
    *(f16x8*)&AhS[BUF][ar0][asw0] = hv; *(f16x8*)&AlS[BUF][ar0][asw0] = lv; \
    split8f(La2, La3, hv, lv); \
    *(f16x8*)&AhS[BUF][ar1][asw1] = hv; *(f16x8*)&AlS[BUF][ar1][asw1] = lv; \
    split8f(Lb0, Lb1, hv, lv); \
    *(f16x8*)&BhS[BUF][ar0][asw0] = hv; *(f16x8*)&BlS[BUF][ar0][asw0] = lv; \
    split8f(Lb2, Lb3, hv, lv); \
    *(f16x8*)&BhS[BUF][ar1][asw1] = hv; *(f16x8*)&BlS[BUF][ar1][asw1] = lv; \
} while (0)

    f32x4 acc1[4][4], acc2[4][4];
    #pragma unroll
    for (int mr = 0; mr < 4; ++mr)
        #pragma unroll
        for (int nr = 0; nr < 4; ++nr) {
            acc1[mr][nr] = (f32x4){0.f, 0.f, 0.f, 0.f};
            acc2[mr][nr] = (f32x4){0.f, 0.f, 0.f, 0.f};
        }

    PLOAD(0);
    PWRITE(0);
    __syncthreads();

    int sw8 = (g ^ ((r >> 1) & 3)) * 8;
    for (int t = 0; t < PNT; ++t) {
        int cur = t & 1;
        if (t + 1 < PNT) PLOAD(t + 1);
        f16x8 bhf[4], blf[4];
        #pragma unroll
        for (int nr = 0; nr < 4; ++nr) {
            int row = wn * 64 + nr * 16 + r;
            bhf[nr] = *(const f16x8*)&BhS[cur][row][sw8];
            blf[nr] = *(const f16x8*)&BlS[cur][row][sw8];
        }
        #pragma unroll
        for (int mr = 0; mr < 4; ++mr) {
            int row = wm * 64 + mr * 16 + r;
            f16x8 ah = *(const f16x8*)&AhS[cur][row][sw8];
            f16x8 al = *(const f16x8*)&AlS[cur][row][sw8];
            #pragma unroll
            for (int nr = 0; nr < 4; ++nr) {
                acc1[mr][nr] = __builtin_amdgcn_mfma_f32_16x16x32_f16(ah, bhf[nr], acc1[mr][nr], 0, 0, 0);
                acc2[mr][nr] = __builtin_amdgcn_mfma_f32_16x16x32_f16(ah, blf[nr], acc2[mr][nr], 0, 0, 0);
                acc2[mr][nr] = __builtin_amdgcn_mfma_f32_16x16x32_f16(al, bhf[nr], acc2[mr][nr], 0, 0, 0);
            }
        }
        if (t + 1 < PNT) PWRITE(cur ^ 1);
        __syncthreads();
    }

    #pragma unroll
    for (int mr = 0; mr < 4; ++mr)
        #pragma unroll
        for (int nr = 0; nr < 4; ++nr)
            #pragma unroll
            for (int j = 0; j < 4; ++j) {
                float C = (acc1[mr][nr][j] + acc2[mr][nr][j] * (1.0f / 2048.0f)) * oscale;
                size_t m = (size_t)(m0 + wm * 64 + mr * 16 + g * 4 + j);
                size_t n = (size_t)(ncol0 + wn * 64 + nr * 16 + r);
                _Float16 hh = (_Float16)C;
                Hout[m * Dm + n] = hh;
                Lout[m * Dm + n] = (_Float16)((C - (float)hh) * 2048.0f);
            }
#undef PLOAD
#undef PWRITE
}

// ---------------- vo[b][h][l] = hidden[b,l,:] . Wvo[h,:]
__global__ void vo_kernel(const float* __restrict__ hidden, const float* __restrict__ Wvo,
                          float* __restrict__ vo) {
    int bh = blockIdx.x;           // 0..31
    int b = bh >> 3, h = bh & 7;
    int l = blockIdx.y * 256 + threadIdx.x;
    __shared__ float w[Dm];
    for (int i = threadIdx.x; i < Dm; i += 256) w[i] = Wvo[h * Dm + i];
    __syncthreads();
    const float* hr = hidden + ((size_t)b * Lseq + l) * Dm;
    float a0 = 0.f, a1 = 0.f, a2 = 0.f, a3 = 0.f;
    #pragma unroll 8
    for (int c = 0; c < Dm; c += 4) {
        float4 v = *(const float4*)(hr + c);
        a0 += v.x * w[c]; a1 += v.y * w[c + 1]; a2 += v.z * w[c + 2]; a3 += v.w * w[c + 3];
    }
    vo[(size_t)bh * Lseq + l] = (a0 + a1) + (a2 + a3);
}

// ---------------- MFMA attention (R4-exact structure + R10-proven trims):
// KSPLIT=1, 512 blocks, 2/CU, full vos, blpart direct; scale folded in K, __expf.
__global__ void __launch_bounds__(256, 2) attn_mfma_kernel(
    const _Float16* __restrict__ Qhp, const _Float16* __restrict__ Qlp,
    const _Float16* __restrict__ Khp, const _Float16* __restrict__ Klp,
    const float* __restrict__ vo, float* __restrict__ blpart) {
    int tid = threadIdx.x;
    int wid = tid >> 6, lane = tid & 63;
    int blk = blockIdx.x;
    int bh = blk & 31;             // same-bh blocks -> same XCD (blk%8 = bh%8)
    int qblk = blk >> 5;           // 0..15
    int b = bh >> 3, h = bh & 7;
    int q0 = qblk * QBLK + wid * 32;
    int r = lane & 15, g = lane >> 4;

    __shared__ _Float16 KhS[2][KT][64];
    __shared__ _Float16 KlS[2][KT][64];
    __shared__ float vos[Lseq];

    const _Float16* Kh_g = Khp + ((size_t)b * Lseq) * Dm + h * HD;
    const _Float16* Kl_g = Klp + ((size_t)b * Lseq) * Dm + h * HD;

    // staging coords: 512 16B-chunks per plane, 2 per thread
    int c0 = tid * 2, c1 = tid * 2 + 1;
    int sr0 = c0 >> 3, so0 = (c0 & 7) * 8;
    int sr1 = c1 >> 3, so1 = (c1 & 7) * 8;
    int dw0 = (so0 ^ ((sr0 & 7) << 3));
    int dw1 = (so1 ^ ((sr1 & 7) << 3));

    // prologue: issue tile-0 loads
    f16x8 nh0 = *(const f16x8*)(Kh_g + (size_t)sr0 * Dm + so0);
    f16x8 nh1 = *(const f16x8*)(Kh_g + (size_t)sr1 * Dm + so1);
    f16x8 nl0 = *(const f16x8*)(Kl_g + (size_t)sr0 * Dm + so0);
    f16x8 nl1 = *(const f16x8*)(Kl_g + (size_t)sr1 * Dm + so1);

    // Q fragments (2 per wave)
    f16x8 Qh[2][2], Ql[2][2];
    #pragma unroll
    for (int f = 0; f < 2; ++f) {
        size_t qbase = ((size_t)(b * Lseq + q0 + f * 16 + r)) * Dm + h * HD + g * 8;
        Qh[f][0] = *(const f16x8*)(Qhp + qbase);
        Qh[f][1] = *(const f16x8*)(Qhp + qbase + 32);
        Ql[f][0] = *(const f16x8*)(Qlp + qbase);
        Ql[f][1] = *(const f16x8*)(Qlp + qbase + 32);
    }

    // vo row into LDS
    for (int i = tid; i < Lseq; i += 256) vos[i] = vo[(size_t)bh * Lseq + i];

    // write tile 0
    *(f16x8*)&KhS[0][sr0][dw0] = nh0;
    *(f16x8*)&KhS[0][sr1][dw1] = nh1;
    *(f16x8*)&KlS[0][sr0][dw0] = nl0;
    *(f16x8*)&KlS[0][sr1][dw1] = nl1;
    __syncthreads();

    double Yd[2] = {0.0, 0.0}, Zd[2] = {0.0, 0.0};
    int i0 = (g * 8) ^ ((r & 7) << 3);

    for (int t = 0; t < NT; ++t) {
        int cur = t & 1;
        if (t + 1 < NT) {
            size_t kn = (size_t)(t + 1) * KT;
            nh0 = *(const f16x8*)(Kh_g + (kn + sr0) * Dm + so0);
            nh1 = *(const f16x8*)(Kh_g + (kn + sr1) * Dm + so1);
            nl0 = *(const f16x8*)(Kl_g + (kn + sr0) * Dm + so0);
            nl1 = *(const f16x8*)(Kl_g + (kn + sr1) * Dm + so1);
        }
        float Yt[2] = {0.f, 0.f}, Zt[2] = {0.f, 0.f};
        #pragma unroll
        for (int s = 0; s < 4; ++s) {
            int row = s * 16 + r;
            f16x8 ah0 = *(const f16x8*)&KhS[cur][row][i0];
            f16x8 ah1 = *(const f16x8*)&KhS[cur][row][i0 ^ 32];
            f16x8 al0 = *(const f16x8*)&KlS[cur][row][i0];
            f16x8 al1 = *(const f16x8*)&KlS[cur][row][i0 ^ 32];
            float4 vkv = *(const float4*)&vos[t * KT + s * 16 + g * 4];
            float vk[4] = {vkv.x, vkv.y, vkv.z, vkv.w};
            #pragma unroll
            for (int f = 0; f < 2; ++f) {
                f32x4 acc1 = {0.f, 0.f, 0.f, 0.f};
                f32x4 acc2 = {0.f, 0.f, 0.f, 0.f};
                acc1 = __builtin_amdgcn_mfma_f32_16x16x32_f16(ah0, Qh[f][0], acc1, 0, 0, 0);
                acc1 = __builtin_amdgcn_mfma_f32_16x16x32_f16(ah1, Qh[f][1], acc1, 0, 0, 0);
                acc2 = __builtin_amdgcn_mfma_f32_16x16x32_f16(ah0, Ql[f][0], acc2, 0, 0, 0);
                acc2 = __builtin_amdgcn_mfma_f32_16x16x32_f16(ah1, Ql[f][1], acc2, 0, 0, 0);
                acc2 = __builtin_amdgcn_mfma_f32_16x16x32_f16(al0, Qh[f][0], acc2, 0, 0, 0);
                acc2 = __builtin_amdgcn_mfma_f32_16x16x32_f16(al1, Qh[f][1], acc2, 0, 0, 0);
                float Ych = 0.f, Zch = 0.f;
                #pragma unroll
                for (int j = 0; j < 4; ++j) {
                    float e = __expf(fmaf(acc2[j], 1.0f / 2048.0f, acc1[j]));
                    Ych += e * vk[j];
                    Zch += e;
                }
                Yt[f] += Ych;
                Zt[f] += Zch;
            }
        }
        Yd[0] += (double)Yt[0]; Zd[0] += (double)Zt[0];
        Yd[1] += (double)Yt[1]; Zd[1] += (double)Zt[1];
        if (t + 1 < NT) {
            int nxt = cur ^ 1;
            *(f16x8*)&KhS[nxt][sr0][dw0] = nh0;
            *(f16x8*)&KhS[nxt][sr1][dw1] = nh1;
            *(f16x8*)&KlS[nxt][sr0][dw0] = nl0;
            *(f16x8*)&KlS[nxt][sr1][dw1] = nl1;
        }
        __syncthreads();
    }

    #pragma unroll
    for (int f = 0; f < 2; ++f) {
        double Y = Yd[f], Z = Zd[f];
        Y += __shfl_xor(Y, 16, 64);
        Y += __shfl_xor(Y, 32, 64);
        Z += __shfl_xor(Z, 16, 64);
        Z += __shfl_xor(Z, 32, 64);
        if (lane < 16)
            blpart[(size_t)bh * Lseq + q0 + f * 16 + lane] = (float)(Y / Z);
    }
}

// ---------------- boundary logits -> hard bits (replicating reference fp path)
__global__ void blhard_kernel(const float* __restrict__ blpart, const float* __restrict__ u,
                              int* __restrict__ hard) {
    int i = blockIdx.x * 256 + threadIdx.x;   // b*L + l
    int b = i >> 11, l = i & (Lseq - 1);
    float bl = 0.f;
    #pragma unroll
    for (int h = 0; h < Hh; ++h)
        bl += blpart[((size_t)(b * Hh + h)) * Lseq + l];
    float x = bl + 1.0f;                       // + boundary_scores (== 1 exactly)
    float probs = 1.0f / (1.0f + expf(-x));
    probs = fminf(fmaxf(probs, 0.0f), 1.0f);
    float pl = logf(probs) - log1pf(-probs);
    float un = u[i];
    float noise = logf(un) - log1pf(-un);
    float t = pl + noise;
    float soft = 1.0f / (1.0f + expf(-t));
    hard[i] = (soft > 0.5f) ? 1 : 0;
}

// ---------------- per-batch scan: segment starts/ends + boundary count
__global__ void scan_kernel(const int* __restrict__ hard, int* __restrict__ segstart,
                            int* __restrict__ segend, int* __restrict__ kcount) {
    int b = blockIdx.x;
    int tid = threadIdx.x;
    __shared__ int hs[Lseq];
    __shared__ int chunk[256];
    for (int i = tid; i < Lseq; i += 256) {
        segstart[b * Lseq + i] = 0;
        segend[b * Lseq + i] = 0;
    }
    int base = b * Lseq;
    int sum = 0;
    int loc[8];
    #pragma unroll
    for (int j = 0; j < 8; ++j) {
        int v = hard[base + tid * 8 + j];
        hs[tid * 8 + j] = v;
        loc[j] = sum;
        sum += v;
    }
    chunk[tid] = sum;
    __syncthreads();
    for (int off = 1; off < 256; off <<= 1) {
        int v = (tid >= off) ? chunk[tid - off] : 0;
        __syncthreads();
        chunk[tid] += v;
        __syncthreads();
    }
    int ebase = chunk[tid] - sum;  // exclusive prefix of chunks
    #pragma unroll
    for (int j = 0; j < 8; ++j) {
        int ll = tid * 8 + j;
        int id = ebase + loc[j];
        if (ll == 0 || hs[ll - 1] == 1) segstart[b * Lseq + id] = ll;
        if (ll == Lseq - 1 || hs[ll] == 1) segend[b * Lseq + id] = ll + 1;
    }
    if (tid == 255) kcount[b] = chunk[255];
}

// ---------------- pooled[b,s,d] = mean of hidden over segment range (0 if empty)
__global__ void pool_kernel(const float* __restrict__ hidden, const int* __restrict__ segstart,
                            const int* __restrict__ segend, float* __restrict__ out) {
    int i = blockIdx.x * 256 + threadIdx.x;     // < B*L*D = 2^22
    int d = i & (Dm - 1);
    int s = (i >> 9) & (Lseq - 1);
    int b = i >> 20;
    int st = segstart[b * Lseq + s];
    int en = segend[b * Lseq + s];
    int n = en - st;
    float acc = 0.f;
    for (int l = st; l < en; ++l)
        acc += hidden[((size_t)b * Lseq + l) * Dm + d];
    out[i] = (n > 0) ? acc / (float)n : 0.0f;
}

// ---------------- binomial log-prob loss
__global__ void loss_kernel(const int* __restrict__ kcount, float* __restrict__ out) {
    if (threadIdx.x == 0 && blockIdx.x == 0) {
        float n = (float)Lseq;
        float acc = 0.f;
        for (int b = 0; b < Bsz; ++b) {
            float k = (float)kcount[b];
            float lp = lgammaf(n + 1.0f) - lgammaf(k + 1.0f) - lgammaf(n - k + 1.0f)
                     + k * logf(0.2f) + (n - k) * log1pf(-0.2f);
            acc += lp;
        }
        out[(size_t)Bsz * Lseq * Dm] = -(acc / (float)Bsz) / n;
    }
}

extern "C" void kernel_launch(void* const* d_in, const int* in_sizes, int n_in,
                              void* d_out, int out_size, void* d_ws, size_t ws_size,
                              hipStream_t stream) {
    const float* hidden = (const float*)d_in[0];
    const float* Wq = (const float*)d_in[1];
    const float* Wk = (const float*)d_in[2];
    const float* Wv = (const float*)d_in[3];
    const float* Wo = (const float*)d_in[4];
    const float* u  = (const float*)d_in[5];
    float* out = (float*)d_out;

    char* ws = (char*)d_ws;
    size_t off = 0;
    const size_t plane = (size_t)Bsz * Lseq * Dm * sizeof(_Float16);   // 8 MB
    _Float16* Qhp = (_Float16*)(ws + off); off += plane;
    _Float16* Qlp = (_Float16*)(ws + off); off += plane;
    _Float16* Khp = (_Float16*)(ws + off); off += plane;
    _Float16* Klp = (_Float16*)(ws + off); off += plane;
    float* Wvo = (float*)(ws + off); off += (size_t)Hh * Dm * 4;
    float* vo = (float*)(ws + off);  off += (size_t)Bsz * Hh * Lseq * 4;
    float* blpart = (float*)(ws + off); off += (size_t)Bsz * Hh * Lseq * 4;
    int* hard = (int*)(ws + off);    off += (size_t)Bsz * Lseq * 4;
    int* segstart = (int*)(ws + off); off += (size_t)Bsz * Lseq * 4;
    int* segend = (int*)(ws + off);  off += (size_t)Bsz * Lseq * 4;
    int* kcount = (int*)(ws + off);  off += 64;

    wvo_kernel<<<dim3(16), dim3(256), 0, stream>>>(Wv, Wo, Wvo);
    proj_mfma_kernel<<<dim3((Bsz * Lseq) / 128, 8), dim3(256), 0, stream>>>(
        hidden, Wq, Wk, Qhp, Qlp, Khp, Klp);
    vo_kernel<<<dim3(Bsz * Hh, Lseq / 256), dim3(256), 0, stream>>>(hidden, Wvo, vo);
    attn_mfma_kernel<<<dim3(32 * (Lseq / QBLK)), dim3(256), 0, stream>>>(
        Qhp, Qlp, Khp, Klp, vo, blpart);
    blhard_kernel<<<dim3((Bsz * Lseq) / 256), dim3(256), 0, stream>>>(blpart, u, hard);
    scan_kernel<<<dim3(Bsz), dim3(256), 0, stream>>>(hard, segstart, segend, kcount);
    pool_kernel<<<dim3((Bsz * Lseq * Dm) / 256), dim3(256), 0, stream>>>(hidden, segstart, segend, out);
    loss_kernel<<<dim3(1), dim3(64), 0, stream>>>(kcount, out);
}

// Round 13
// 138.446 us; speedup vs baseline: 2.4123x; 1.0257x over previous
//
#include <hip/hip_runtime.h>
#include <hip/hip_bf16.h>

#define Bsz 4
#define Lseq 2048
#define Dm 512
#define Hh 8
#define HD 64
#define QBLK 128
#define KT 64
#define NT (Lseq / KT)
#define PNT (Dm / 32)

typedef __attribute__((ext_vector_type(8))) _Float16 f16x8;
typedef __attribute__((ext_vector_type(4))) float f32x4;

// ---------------- Wvo fold: Wvo[h][c] = sum_d Wv[(h*64+d)*512 + c] * Wo[h*64+d]
__global__ void wvo_kernel(const float* __restrict__ Wv, const float* __restrict__ Wo,
                           float* __restrict__ Wvo) {
    int h = blockIdx.x >> 1;
    int c = (blockIdx.x & 1) * 256 + threadIdx.x;
    float acc = 0.f;
    #pragma unroll 8
    for (int d = 0; d < HD; ++d)
        acc += Wv[(size_t)(h * HD + d) * Dm + c] * Wo[h * HD + d];
    Wvo[h * Dm + c] = acc;
}

__device__ __forceinline__ void split8f(float4 x, float4 y, f16x8& h, f16x8& l) {
    float v[8] = {x.x, x.y, x.z, x.w, y.x, y.y, y.z, y.w};
    #pragma unroll
    for (int j = 0; j < 8; ++j) {
        _Float16 hh = (_Float16)v[j];
        h[j] = hh;
        l[j] = (_Float16)((v[j] - (float)hh) * 2048.0f);
    }
}

// ---------------- MFMA projection: C = hidden @ Wqk^T via f16x3 emulation.
// K output scaled by 0.125 (exact pow2 -> bit-exact score scaling folded in).
__global__ void __launch_bounds__(256, 2) proj_mfma_kernel(
    const float* __restrict__ A,
    const float* __restrict__ Wq, const float* __restrict__ Wk,
    _Float16* __restrict__ Qhp, _Float16* __restrict__ Qlp,
    _Float16* __restrict__ Khp, _Float16* __restrict__ Klp) {
    __shared__ _Float16 AhS[2][128][32];
    __shared__ _Float16 AlS[2][128][32];
    __shared__ _Float16 BhS[2][128][32];
    __shared__ _Float16 BlS[2][128][32];

    int tid = threadIdx.x;
    int lane = tid & 63, wid = tid >> 6;
    int wm = wid >> 1, wn = wid & 1;
    int r = lane & 15, g = lane >> 4;
    int m0 = blockIdx.x * 128;
    int nblk = blockIdx.y;
    bool isQ = nblk < 4;
    const float* Wsrc = isQ ? (Wq + (size_t)nblk * 128 * Dm)
                            : (Wk + (size_t)(nblk - 4) * 128 * Dm);
    _Float16* Hout = isQ ? Qhp : Khp;
    _Float16* Lout = isQ ? Qlp : Klp;
    int ncol0 = (nblk & 3) * 128;
    float oscale = isQ ? 1.0f : 0.125f;   // SCALE folded into K (pow2: bit-exact)

    int c0 = tid * 2, c1 = tid * 2 + 1;
    int ar0 = c0 >> 2, akc0 = c0 & 3;
    int ar1 = c1 >> 2, akc1 = c1 & 3;
    int asw0 = (akc0 ^ ((ar0 >> 1) & 3)) * 8;
    int asw1 = (akc1 ^ ((ar1 >> 1) & 3)) * 8;

    const float* Abase = A + (size_t)m0 * Dm;

    float4 La0, La1, La2, La3, Lb0, Lb1, Lb2, Lb3;

#define PLOAD(T) do { \
    const float* ap0 = Abase + (size_t)ar0 * Dm + (T) * 32 + akc0 * 8; \
    const float* ap1 = Abase + (size_t)ar1 * Dm + (T) * 32 + akc1 * 8; \
    const float* bp0 = Wsrc + (size_t)ar0 * Dm + (T) * 32 + akc0 * 8; \
    const float* bp1 = Wsrc + (size_t)ar1 * Dm + (T) * 32 + akc1 * 8; \
    La0 = *(const float4*)ap0; La1 = *(const float4*)(ap0 + 4); \
    La2 = *(const float4*)ap1; La3 = *(const float4*)(ap1 + 4); \
    Lb0 = *(const float4*)bp0; Lb1 = *(const float4*)(bp0 + 4); \
    Lb2 = *(const float4*)bp1; Lb3 = *(const float4*)(bp1 + 4); \
} while (0)

#define PWRITE(BUF) do { \
    f16x8 hv, lv; \
    split8f(La0, La1, hv, lv); \
    *(f16x8*)&AhS[BUF][ar0][asw0] = hv; *(f16x8*)&AlS[BUF][ar0][asw0] = lv; \
    split8f(La2, La3, hv, lv); \
    *(f16x8*)&AhS[BUF][ar1][asw1] = hv; *(f16x8*)&AlS[BUF][ar1][asw1] = lv; \
    split8f(Lb0, Lb1, hv, lv); \
    *(f16x8*)&BhS[BUF][ar0][asw0] = hv; *(f16x8*)&BlS[BUF][ar0][asw0] = lv; \
    split8f(Lb2, Lb3, hv, lv); \
    *(f16x8*)&BhS[BUF][ar1][asw1] = hv; *(f16x8*)&BlS[BUF][ar1][asw1] = lv; \
} while (0)

    f32x4 acc1[4][4], acc2[4][4];
    #pragma unroll
    for (int mr = 0; mr < 4; ++mr)
        #pragma unroll
        for (int nr = 0; nr < 4; ++nr) {
            acc1[mr][nr] = (f32x4){0.f, 0.f, 0.f, 0.f};
            acc2[mr][nr] = (f32x4){0.f, 0.f, 0.f, 0.f};
        }

    PLOAD(0);
    PWRITE(0);
    __syncthreads();

    int sw8 = (g ^ ((r >> 1) & 3)) * 8;
    for (int t = 0; t < PNT; ++t) {
        int cur = t & 1;
        if (t + 1 < PNT) PLOAD(t + 1);
        f16x8 bhf[4], blf[4];
        #pragma unroll
        for (int nr = 0; nr < 4; ++nr) {
            int row = wn * 64 + nr * 16 + r;
            bhf[nr] = *(const f16x8*)&BhS[cur][row][sw8];
            blf[nr] = *(const f16x8*)&BlS[cur][row][sw8];
        }
        #pragma unroll
        for (int mr = 0; mr < 4; ++mr) {
            int row = wm * 64 + mr * 16 + r;
            f16x8 ah = *(const f16x8*)&AhS[cur][row][sw8];
            f16x8 al = *(const f16x8*)&AlS[cur][row][sw8];
            #pragma unroll
            for (int nr = 0; nr < 4; ++nr) {
                acc1[mr][nr] = __builtin_amdgcn_mfma_f32_16x16x32_f16(ah, bhf[nr], acc1[mr][nr], 0, 0, 0);
                acc2[mr][nr] = __builtin_amdgcn_mfma_f32_16x16x32_f16(ah, blf[nr], acc2[mr][nr], 0, 0, 0);
                acc2[mr][nr] = __builtin_amdgcn_mfma_f32_16x16x32_f16(al, bhf[nr], acc2[mr][nr], 0, 0, 0);
            }
        }
        if (t + 1 < PNT) PWRITE(cur ^ 1);
        __syncthreads();
    }

    #pragma unroll
    for (int mr = 0; mr < 4; ++mr)
        #pragma unroll
        for (int nr = 0; nr < 4; ++nr)
            #pragma unroll
            for (int j = 0; j < 4; ++j) {
                float C = (acc1[mr][nr][j] + acc2[mr][nr][j] * (1.0f / 2048.0f)) * oscale;
                size_t m = (size_t)(m0 + wm * 64 + mr * 16 + g * 4 + j);
                size_t n = (size_t)(ncol0 + wn * 64 + nr * 16 + r);
                _Float16 hh = (_Float16)C;
                Hout[m * Dm + n] = hh;
                Lout[m * Dm + n] = (_Float16)((C - (float)hh) * 2048.0f);
            }
#undef PLOAD
#undef PWRITE
}

// ---------------- vo[b][h][l] = hidden[b,l,:] . Wvo[h,:]
__global__ void vo_kernel(const float* __restrict__ hidden, const float* __restrict__ Wvo,
                          float* __restrict__ vo) {
    int bh = blockIdx.x;           // 0..31
    int b = bh >> 3, h = bh & 7;
    int l = blockIdx.y * 256 + threadIdx.x;
    __shared__ float w[Dm];
    for (int i = threadIdx.x; i < Dm; i += 256) w[i] = Wvo[h * Dm + i];
    __syncthreads();
    const float* hr = hidden + ((size_t)b * Lseq + l) * Dm;
    float a0 = 0.f, a1 = 0.f, a2 = 0.f, a3 = 0.f;
    #pragma unroll 8
    for (int c = 0; c < Dm; c += 4) {
        float4 v = *(const float4*)(hr + c);
        a0 += v.x * w[c]; a1 += v.y * w[c + 1]; a2 += v.z * w[c + 2]; a3 += v.w * w[c + 3];
    }
    vo[(size_t)bh * Lseq + l] = (a0 + a1) + (a2 + a3);
}

// ---------------- MFMA attention v10: R12 structure + depth-2 register prefetch.
// Two named staging sets (sA/sB); tile t+2 issued at iter t, so the LDS write of
// tile t+1 waits on loads issued a full iteration earlier (counted vmcnt slack).
__global__ void __launch_bounds__(256, 2) attn_mfma_kernel(
    const _Float16* __restrict__ Qhp, const _Float16* __restrict__ Qlp,
    const _Float16* __restrict__ Khp, const _Float16* __restrict__ Klp,
    const float* __restrict__ vo, float* __restrict__ blpart) {
    int tid = threadIdx.x;
    int wid = tid >> 6, lane = tid & 63;
    int blk = blockIdx.x;
    int bh = blk & 31;             // same-bh blocks -> same XCD (blk%8 = bh%8)
    int qblk = blk >> 5;           // 0..15
    int b = bh >> 3, h = bh & 7;
    int q0 = qblk * QBLK + wid * 32;
    int r = lane & 15, g = lane >> 4;

    __shared__ _Float16 KhS[2][KT][64];
    __shared__ _Float16 KlS[2][KT][64];
    __shared__ float vos[Lseq];

    const _Float16* Kh_g = Khp + ((size_t)b * Lseq) * Dm + h * HD;
    const _Float16* Kl_g = Klp + ((size_t)b * Lseq) * Dm + h * HD;

    // staging coords: 512 16B-chunks per plane, 2 per thread
    int c0 = tid * 2, c1 = tid * 2 + 1;
    int sr0 = c0 >> 3, so0 = (c0 & 7) * 8;
    int sr1 = c1 >> 3, so1 = (c1 & 7) * 8;
    int dw0 = (so0 ^ ((sr0 & 7) << 3));
    int dw1 = (so1 ^ ((sr1 & 7) << 3));

    f16x8 sAh0, sAh1, sAl0, sAl1;
    f16x8 sBh0, sBh1, sBl0, sBl1;

#define LOADSET(S, T) do { \
    size_t kn_ = (size_t)(T) * KT; \
    S##h0 = *(const f16x8*)(Kh_g + (kn_ + sr0) * Dm + so0); \
    S##h1 = *(const f16x8*)(Kh_g + (kn_ + sr1) * Dm + so1); \
    S##l0 = *(const f16x8*)(Kl_g + (kn_ + sr0) * Dm + so0); \
    S##l1 = *(const f16x8*)(Kl_g + (kn_ + sr1) * Dm + so1); \
} while (0)

#define WRITESET(S, BUF) do { \
    *(f16x8*)&KhS[BUF][sr0][dw0] = S##h0; \
    *(f16x8*)&KhS[BUF][sr1][dw1] = S##h1; \
    *(f16x8*)&KlS[BUF][sr0][dw0] = S##l0; \
    *(f16x8*)&KlS[BUF][sr1][dw1] = S##l1; \
} while (0)

#define COMPUTE(BUF, T) do { \
    float Yt[2] = {0.f, 0.f}, Zt[2] = {0.f, 0.f}; \
    _Pragma("unroll") \
    for (int s = 0; s < 4; ++s) { \
        int row = s * 16 + r; \
        f16x8 ah0 = *(const f16x8*)&KhS[BUF][row][i0]; \
        f16x8 ah1 = *(const f16x8*)&KhS[BUF][row][i0 ^ 32]; \
        f16x8 al0 = *(const f16x8*)&KlS[BUF][row][i0]; \
        f16x8 al1 = *(const f16x8*)&KlS[BUF][row][i0 ^ 32]; \
        float4 vkv = *(const float4*)&vos[(T) * KT + s * 16 + g * 4]; \
        float vk[4] = {vkv.x, vkv.y, vkv.z, vkv.w}; \
        _Pragma("unroll") \
        for (int f = 0; f < 2; ++f) { \
            f32x4 acc1 = {0.f, 0.f, 0.f, 0.f}; \
            f32x4 acc2 = {0.f, 0.f, 0.f, 0.f}; \
            acc1 = __builtin_amdgcn_mfma_f32_16x16x32_f16(ah0, Qh[f][0], acc1, 0, 0, 0); \
            acc1 = __builtin_amdgcn_mfma_f32_16x16x32_f16(ah1, Qh[f][1], acc1, 0, 0, 0); \
            acc2 = __builtin_amdgcn_mfma_f32_16x16x32_f16(ah0, Ql[f][0], acc2, 0, 0, 0); \
            acc2 = __builtin_amdgcn_mfma_f32_16x16x32_f16(ah1, Ql[f][1], acc2, 0, 0, 0); \
            acc2 = __builtin_amdgcn_mfma_f32_16x16x32_f16(al0, Qh[f][0], acc2, 0, 0, 0); \
            acc2 = __builtin_amdgcn_mfma_f32_16x16x32_f16(al1, Qh[f][1], acc2, 0, 0, 0); \
            float Ych = 0.f, Zch = 0.f; \
            _Pragma("unroll") \
            for (int j = 0; j < 4; ++j) { \
                float e = __expf(fmaf(acc2[j], 1.0f / 2048.0f, acc1[j])); \
                Ych += e * vk[j]; \
                Zch += e; \
            } \
            Yt[f] += Ych; \
            Zt[f] += Zch; \
        } \
    } \
    Yd[0] += (double)Yt[0]; Zd[0] += (double)Zt[0]; \
    Yd[1] += (double)Yt[1]; Zd[1] += (double)Zt[1]; \
} while (0)

    // prologue: tile0 -> sA, tile1 -> sB (both in flight)
    LOADSET(sA, 0);
    LOADSET(sB, 1);

    // Q fragments (2 per wave)
    f16x8 Qh[2][2], Ql[2][2];
    #pragma unroll
    for (int f = 0; f < 2; ++f) {
        size_t qbase = ((size_t)(b * Lseq + q0 + f * 16 + r)) * Dm + h * HD + g * 8;
        Qh[f][0] = *(const f16x8*)(Qhp + qbase);
        Qh[f][1] = *(const f16x8*)(Qhp + qbase + 32);
        Ql[f][0] = *(const f16x8*)(Qlp + qbase);
        Ql[f][1] = *(const f16x8*)(Qlp + qbase + 32);
    }

    // vo row into LDS
    for (int i = tid; i < Lseq; i += 256) vos[i] = vo[(size_t)bh * Lseq + i];

    WRITESET(sA, 0);   // waits only on tile0's loads (vmcnt(4)); tile1 stays in flight
    __syncthreads();

    double Yd[2] = {0.0, 0.0}, Zd[2] = {0.0, 0.0};
    int i0 = (g * 8) ^ ((r & 7) << 3);

    #pragma unroll 1
    for (int th = 0; th < NT / 2; ++th) {
        int t0 = th * 2;
        // even iter: compute buf0 (tile t0); prefetch t0+2 into sA; write sB (t0+1) -> buf1
        if (t0 + 2 < NT) LOADSET(sA, t0 + 2);
        COMPUTE(0, t0);
        WRITESET(sB, 1);
        __syncthreads();
        // odd iter: compute buf1 (tile t0+1); prefetch t0+3 into sB; write sA (t0+2) -> buf0
        if (t0 + 3 < NT) LOADSET(sB, t0 + 3);
        COMPUTE(1, t0 + 1);
        if (t0 + 2 < NT) WRITESET(sA, 0);
        __syncthreads();
    }
#undef LOADSET
#undef WRITESET
#undef COMPUTE

    #pragma unroll
    for (int f = 0; f < 2; ++f) {
        double Y = Yd[f], Z = Zd[f];
        Y += __shfl_xor(Y, 16, 64);
        Y += __shfl_xor(Y, 32, 64);
        Z += __shfl_xor(Z, 16, 64);
        Z += __shfl_xor(Z, 32, 64);
        if (lane < 16)
            blpart[(size_t)bh * Lseq + q0 + f * 16 + lane] = (float)(Y / Z);
    }
}

// ---------------- boundary logits -> hard bits (replicating reference fp path)
__global__ void blhard_kernel(const float* __restrict__ blpart, const float* __restrict__ u,
                              int* __restrict__ hard) {
    int i = blockIdx.x * 256 + threadIdx.x;   // b*L + l
    int b = i >> 11, l = i & (Lseq - 1);
    float bl = 0.f;
    #pragma unroll
    for (int h = 0; h < Hh; ++h)
        bl += blpart[((size_t)(b * Hh + h)) * Lseq + l];
    float x = bl + 1.0f;                       // + boundary_scores (== 1 exactly)
    float probs = 1.0f / (1.0f + expf(-x));
    probs = fminf(fmaxf(probs, 0.0f), 1.0f);
    float pl = logf(probs) - log1pf(-probs);
    float un = u[i];
    float noise = logf(un) - log1pf(-un);
    float t = pl + noise;
    float soft = 1.0f / (1.0f + expf(-t));
    hard[i] = (soft > 0.5f) ? 1 : 0;
}

// ---------------- per-batch scan: segment starts/ends + boundary count
__global__ void scan_kernel(const int* __restrict__ hard, int* __restrict__ segstart,
                            int* __restrict__ segend, int* __restrict__ kcount) {
    int b = blockIdx.x;
    int tid = threadIdx.x;
    __shared__ int hs[Lseq];
    __shared__ int chunk[256];
    for (int i = tid; i < Lseq; i += 256) {
        segstart[b * Lseq + i] = 0;
        segend[b * Lseq + i] = 0;
    }
    int base = b * Lseq;
    int sum = 0;
    int loc[8];
    #pragma unroll
    for (int j = 0; j < 8; ++j) {
        int v = hard[base + tid * 8 + j];
        hs[tid * 8 + j] = v;
        loc[j] = sum;
        sum += v;
    }
    chunk[tid] = sum;
    __syncthreads();
    for (int off = 1; off < 256; off <<= 1) {
        int v = (tid >= off) ? chunk[tid - off] : 0;
        __syncthreads();
        chunk[tid] += v;
        __syncthreads();
    }
    int ebase = chunk[tid] - sum;  // exclusive prefix of chunks
    #pragma unroll
    for (int j = 0; j < 8; ++j) {
        int ll = tid * 8 + j;
        int id = ebase + loc[j];
        if (ll == 0 || hs[ll - 1] == 1) segstart[b * Lseq + id] = ll;
        if (ll == Lseq - 1 || hs[ll] == 1) segend[b * Lseq + id] = ll + 1;
    }
    if (tid == 255) kcount[b] = chunk[255];
}

// ---------------- pooled[b,s,d] = mean of hidden over segment range (0 if empty)
__global__ void pool_kernel(const float* __restrict__ hidden, const int* __restrict__ segstart,
                            const int* __restrict__ segend, float* __restrict__ out) {
    int i = blockIdx.x * 256 + threadIdx.x;     // < B*L*D = 2^22
    int d = i & (Dm - 1);
    int s = (i >> 9) & (Lseq - 1);
    int b = i >> 20;
    int st = segstart[b * Lseq + s];
    int en = segend[b * Lseq + s];
    int n = en - st;
    float acc = 0.f;
    for (int l = st; l < en; ++l)
        acc += hidden[((size_t)b * Lseq + l) * Dm + d];
    out[i] = (n > 0) ? acc / (float)n : 0.0f;
}

// ---------------- binomial log-prob loss
__global__ void loss_kernel(const int* __restrict__ kcount, float* __restrict__ out) {
    if (threadIdx.x == 0 && blockIdx.x == 0) {
        float n = (float)Lseq;
        float acc = 0.f;
        for (int b = 0; b < Bsz; ++b) {
            float k = (float)kcount[b];
            float lp = lgammaf(n + 1.0f) - lgammaf(k + 1.0f) - lgammaf(n - k + 1.0f)
                     + k * logf(0.2f) + (n - k) * log1pf(-0.2f);
            acc += lp;
        }
        out[(size_t)Bsz * Lseq * Dm] = -(acc / (float)Bsz) / n;
    }
}

extern "C" void kernel_launch(void* const* d_in, const int* in_sizes, int n_in,
                              void* d_out, int out_size, void* d_ws, size_t ws_size,
                              hipStream_t stream) {
    const float* hidden = (const float*)d_in[0];
    const float* Wq = (const float*)d_in[1];
    const float* Wk = (const float*)d_in[2];
    const float* Wv = (const float*)d_in[3];
    const float* Wo = (const float*)d_in[4];
    const float* u  = (const float*)d_in[5];
    float* out = (float*)d_out;

    char* ws = (char*)d_ws;
    size_t off = 0;
    const size_t plane = (size_t)Bsz * Lseq * Dm * sizeof(_Float16);   // 8 MB
    _Float16* Qhp = (_Float16*)(ws + off); off += plane;
    _Float16* Qlp = (_Float16*)(ws + off); off += plane;
    _Float16* Khp = (_Float16*)(ws + off); off += plane;
    _Float16* Klp = (_Float16*)(ws + off); off += plane;
    float* Wvo = (float*)(ws + off); off += (size_t)Hh * Dm * 4;
    float* vo = (float*)(ws + off);  off += (size_t)Bsz * Hh * Lseq * 4;
    float* blpart = (float*)(ws + off); off += (size_t)Bsz * Hh * Lseq * 4;
    int* hard = (int*)(ws + off);    off += (size_t)Bsz * Lseq * 4;
    int* segstart = (int*)(ws + off); off += (size_t)Bsz * Lseq * 4;
    int* segend = (int*)(ws + off);  off += (size_t)Bsz * Lseq * 4;
    int* kcount = (int*)(ws + off);  off += 64;

    wvo_kernel<<<dim3(16), dim3(256), 0, stream>>>(Wv, Wo, Wvo);
    proj_mfma_kernel<<<dim3((Bsz * Lseq) / 128, 8), dim3(256), 0, stream>>>(
        hidden, Wq, Wk, Qhp, Qlp, Khp, Klp);
    vo_kernel<<<dim3(Bsz * Hh, Lseq / 256), dim3(256), 0, stream>>>(hidden, Wvo, vo);
    attn_mfma_kernel<<<dim3(32 * (Lseq / QBLK)), dim3(256), 0, stream>>>(
        Qhp, Qlp, Khp, Klp, vo, blpart);
    blhard_kernel<<<dim3((Bsz * Lseq) / 256), dim3(256), 0, stream>>>(blpart, u, hard);
    scan_kernel<<<dim3(Bsz), dim3(256), 0, stream>>>(hard, segstart, segend, kcount);
    pool_kernel<<<dim3((Bsz * Lseq * Dm) / 256), dim3(256), 0, stream>>>(hidden, segstart, segend, out);
    loss_kernel<<<dim3(1), dim3(64), 0, stream>>>(kcount, out);
}